// Round 1
// baseline (718.158 us; speedup 1.0000x reference)
//
#include <hip/hip_runtime.h>
#include <hip/hip_bf16.h>

#define BN     6
#define NQ     10000
#define DIM    256
#define HEADS  8
#define HDD    32
#define HF_    32
#define WF_    88
#define HW_    (HF_*WF_)     /* 2816 */
#define MTOT   (BN*NQ)       /* 60000 */

// ---------------------------------------------------------------------------
// K0: ebias[n][j] = sum_d (lvl[d]+cam[n][d]) * W_value[j][d] + b_value[j]
// ---------------------------------------------------------------------------
__global__ __launch_bounds__(256)
void k_ebias(const float* __restrict__ lvl, const float* __restrict__ cam,
             const float* __restrict__ Wv, const float* __restrict__ bv,
             float* __restrict__ ebias)
{
    const int n = blockIdx.x;
    const int j = threadIdx.x;
    __shared__ float e[DIM];
    e[j] = lvl[j] + cam[n*DIM + j];
    __syncthreads();
    const float* w = Wv + (size_t)j*DIM;
    float s = bv[j];
    for (int d = 0; d < DIM; ++d) s += e[d]*w[d];
    ebias[n*DIM + j] = s;
}

// ---------------------------------------------------------------------------
// K1: value_t[n][h][p][c] = sum_d features0[n][d][p] * W_value[h*32+c][d] + ebias[n][h*32+c]
// tile: 64 p x 64 j, K=256 in chunks of 16.  block 256 threads, 4x4 microtile.
// ---------------------------------------------------------------------------
__global__ __launch_bounds__(256)
void k_value(const float* __restrict__ feat, const float* __restrict__ Wv,
             const float* __restrict__ ebias, float* __restrict__ value_t)
{
    const int n  = blockIdx.z;
    const int p0 = blockIdx.x * 64;
    const int j0 = blockIdx.y * 64;
    const int tid = threadIdx.x;
    const int tx = tid & 15, ty = tid >> 4;
    __shared__ float As[16][65];
    __shared__ float Bs[16][65];
    float acc[4][4] = {};
    const int ak  = tid >> 4;          // 0..15 (k row for A load)
    const int ap4 = (tid & 15) * 4;    // p offset (float4)
    const int bj  = tid >> 2;          // 0..63 (j row for B load)
    const int bk4 = (tid & 3) * 4;     // k offset (float4)

    for (int k0 = 0; k0 < DIM; k0 += 16) {
        {
            const float4 v = *(const float4*)(feat + (size_t)(n*DIM + k0 + ak)*HW_ + p0 + ap4);
            As[ak][ap4+0]=v.x; As[ak][ap4+1]=v.y; As[ak][ap4+2]=v.z; As[ak][ap4+3]=v.w;
        }
        {
            const float4 w = *(const float4*)(Wv + (size_t)(j0 + bj)*DIM + k0 + bk4);
            Bs[bk4+0][bj]=w.x; Bs[bk4+1][bj]=w.y; Bs[bk4+2][bj]=w.z; Bs[bk4+3][bj]=w.w;
        }
        __syncthreads();
        #pragma unroll
        for (int kk = 0; kk < 16; ++kk) {
            float a[4] = {As[kk][ty], As[kk][ty+16], As[kk][ty+32], As[kk][ty+48]};
            float b[4] = {Bs[kk][tx], Bs[kk][tx+16], Bs[kk][tx+32], Bs[kk][tx+48]};
            #pragma unroll
            for (int i = 0; i < 4; ++i)
                #pragma unroll
                for (int j = 0; j < 4; ++j)
                    acc[i][j] += a[i]*b[j];
        }
        __syncthreads();
    }
    #pragma unroll
    for (int i = 0; i < 4; ++i) {
        const int p = p0 + ty + 16*i;
        #pragma unroll
        for (int jj = 0; jj < 4; ++jj) {
            const int jc = j0 + tx + 16*jj;
            const int h = jc >> 5, c = jc & 31;
            value_t[((size_t)(n*HEADS + h)*HW_ + p)*HDD + c] = acc[i][jj] + ebias[n*DIM + jc];
        }
    }
}

// ---------------------------------------------------------------------------
// K2a: off/attn-logit GEMM: qp = queries+pos (60000x256) times [W_off;W_attn]^T (192x256)
// grid.y selects 64-col slab (0,1 -> off, 2 -> attn logits). biases added here.
// ---------------------------------------------------------------------------
__global__ __launch_bounds__(256)
void k_offattn(const float* __restrict__ Qr, const float* __restrict__ Pe,
               const float* __restrict__ Woff, const float* __restrict__ boff,
               const float* __restrict__ Wattn, const float* __restrict__ battn,
               float* __restrict__ off_ws, float* __restrict__ attw_ws)
{
    const int m0 = blockIdx.x * 64;
    const int j0 = blockIdx.y * 64;
    const int tid = threadIdx.x;
    const int tx = tid & 15, ty = tid >> 4;
    __shared__ float As[16][65];
    __shared__ float Bs[16][65];
    float acc[4][4] = {};
    const int lr  = tid >> 2;        // 0..63
    const int lk4 = (tid & 3) * 4;   // 0,4,8,12

    for (int k0 = 0; k0 < DIM; k0 += 16) {
        {
            const int m = m0 + lr;
            float4 a = make_float4(0.f,0.f,0.f,0.f);
            if (m < MTOT) {
                const float4 x = *(const float4*)(Qr + (size_t)m*DIM + k0 + lk4);
                const float4 y = *(const float4*)(Pe + (size_t)m*DIM + k0 + lk4);
                a = make_float4(x.x+y.x, x.y+y.y, x.z+y.z, x.w+y.w);
            }
            As[lk4+0][lr]=a.x; As[lk4+1][lr]=a.y; As[lk4+2][lr]=a.z; As[lk4+3][lr]=a.w;
        }
        {
            const int j = j0 + lr;
            const float* Wrow = (j < 128) ? (Woff + (size_t)j*DIM) : (Wattn + (size_t)(j-128)*DIM);
            const float4 w = *(const float4*)(Wrow + k0 + lk4);
            Bs[lk4+0][lr]=w.x; Bs[lk4+1][lr]=w.y; Bs[lk4+2][lr]=w.z; Bs[lk4+3][lr]=w.w;
        }
        __syncthreads();
        #pragma unroll
        for (int kk = 0; kk < 16; ++kk) {
            float a[4] = {As[kk][ty], As[kk][ty+16], As[kk][ty+32], As[kk][ty+48]};
            float b[4] = {Bs[kk][tx], Bs[kk][tx+16], Bs[kk][tx+32], Bs[kk][tx+48]};
            #pragma unroll
            for (int i = 0; i < 4; ++i)
                #pragma unroll
                for (int j = 0; j < 4; ++j)
                    acc[i][j] += a[i]*b[j];
        }
        __syncthreads();
    }
    #pragma unroll
    for (int i = 0; i < 4; ++i) {
        const int m = m0 + ty + 16*i;
        if (m >= MTOT) continue;
        #pragma unroll
        for (int jj = 0; jj < 4; ++jj) {
            const int j = j0 + tx + 16*jj;
            const float v = acc[i][jj];
            if (j < 128) off_ws [(size_t)m*128 + j]       = v + boff[j];
            else         attw_ws[(size_t)m*64  + (j-128)] = v + battn[j-128];
        }
    }
}

// ---------------------------------------------------------------------------
// K2b: sampling. thread = (query-in-tile, head). softmax(8) + 8pts x 4corner
// bilinear gather of 32-ch rows from value_t, weighted into combined[n][q][h*32+c].
// ---------------------------------------------------------------------------
__global__ __launch_bounds__(256)
void k_sample(const float* __restrict__ value_t, const float* __restrict__ off_ws,
              const float* __restrict__ attw_ws, const float* __restrict__ ref3d,
              float* __restrict__ combined)
{
    const int n = blockIdx.y;
    const int tid = threadIdx.x;
    const int ql = tid >> 3;
    const int h  = tid & 7;
    const int q  = blockIdx.x*32 + ql;
    if (q >= NQ) return;
    const size_t base = (size_t)n*NQ + q;

    const float* offp = off_ws  + base*128 + h*16;
    const float* logp = attw_ws + base*64  + h*8;
    float lg[8];
    float mx = -1e30f;
    #pragma unroll
    for (int p = 0; p < 8; ++p) { lg[p] = logp[p]; mx = fmaxf(mx, lg[p]); }
    float ssum = 0.f;
    #pragma unroll
    for (int p = 0; p < 8; ++p) { lg[p] = expf(lg[p]-mx); ssum += lg[p]; }
    const float inv = 1.f/ssum;

    float rx[4], ry[4];
    #pragma unroll
    for (int z = 0; z < 4; ++z) {
        rx[z] = ref3d[(base*4+z)*2+0];
        ry[z] = ref3d[(base*4+z)*2+1];
    }

    float acc[32];
    #pragma unroll
    for (int c = 0; c < 32; ++c) acc[c] = 0.f;
    const float* vbase = value_t + (size_t)(n*HEADS + h)*HW_*HDD;

    #pragma unroll
    for (int p = 0; p < 8; ++p) {
        const int z = p & 3;                       // p = j*4+z per off_z reshape
        const float ax = rx[z]*WF_ + offp[p*2+0] - 0.5f;
        const float ay = ry[z]*HF_ + offp[p*2+1] - 0.5f;
        const float fx = floorf(ax), fy = floorf(ay);
        const float dx = ax-fx, dy = ay-fy;
        const int x0 = (int)fx, y0 = (int)fy;
        const float wp = lg[p]*inv;
        #pragma unroll
        for (int oy = 0; oy < 2; ++oy) {
            const int yi = y0+oy;
            if (yi < 0 || yi >= HF_) continue;
            const float wy = oy ? dy : 1.f-dy;
            #pragma unroll
            for (int ox = 0; ox < 2; ++ox) {
                const int xi = x0+ox;
                if (xi < 0 || xi >= WF_) continue;
                const float cw = wp * wy * (ox ? dx : 1.f-dx);
                const float4* row = (const float4*)(vbase + (size_t)(yi*WF_+xi)*HDD);
                #pragma unroll
                for (int c4 = 0; c4 < 8; ++c4) {
                    const float4 v = row[c4];
                    acc[c4*4+0] += cw*v.x; acc[c4*4+1] += cw*v.y;
                    acc[c4*4+2] += cw*v.z; acc[c4*4+3] += cw*v.w;
                }
            }
        }
    }
    float4* outp = (float4*)(combined + base*DIM + h*HDD);
    #pragma unroll
    for (int c4 = 0; c4 < 8; ++c4)
        outp[c4] = make_float4(acc[c4*4+0], acc[c4*4+1], acc[c4*4+2], acc[c4*4+3]);
}

// ---------------------------------------------------------------------------
// K3a: camera reduce. asum[q][d] = (1/count) * sum_n hit[n,q]*combined[n][q][d];
// biasf[q] = (hitcount>0) ? 1 : 0  (bias coefficient for inner GEMM).
// ---------------------------------------------------------------------------
__global__ __launch_bounds__(256)
void k_reduce(const float* __restrict__ combined, const int* __restrict__ bev_mask,
              float* __restrict__ asum, float* __restrict__ biasf)
{
    const int q = blockIdx.x;
    const int d = threadIdx.x;
    __shared__ float s_hit[BN];
    __shared__ float s_scale, s_bias;
    if (d < BN) {
        int hit = 0;
        #pragma unroll
        for (int z = 0; z < 4; ++z)
            hit |= (bev_mask[(((size_t)d*NQ + q)*4 + z)*2] != 0);
        s_hit[d] = (float)hit;
    }
    __syncthreads();
    if (d == 0) {
        float c = 0.f;
        for (int nn = 0; nn < BN; ++nn) c += s_hit[nn];
        s_bias  = (c > 0.f) ? 1.f : 0.f;
        s_scale = 1.f / fmaxf(c, 1.f);
    }
    __syncthreads();
    float a = 0.f;
    for (int nn = 0; nn < BN; ++nn)
        a += s_hit[nn] * combined[((size_t)nn*NQ + q)*DIM + d];
    asum[(size_t)q*DIM + d] = a * s_scale;
    if (d == 0) biasf[q] = s_bias;
}

// ---------------------------------------------------------------------------
// K3b/K4: generic 64x64-tiled GEMM: out[m][j] = A[m]·W[j] + f(m)*bias[j]
// rowscale==nullptr -> f=1.
// ---------------------------------------------------------------------------
__global__ __launch_bounds__(256)
void k_gemm_nb(const float* __restrict__ A, const float* __restrict__ W,
               const float* __restrict__ bias, const float* __restrict__ rowscale,
               float* __restrict__ out, int M)
{
    const int m0 = blockIdx.x * 64;
    const int j0 = blockIdx.y * 64;
    const int tid = threadIdx.x;
    const int tx = tid & 15, ty = tid >> 4;
    __shared__ float As[16][65];
    __shared__ float Bs[16][65];
    float acc[4][4] = {};
    const int lr  = tid >> 2;
    const int lk4 = (tid & 3) * 4;

    for (int k0 = 0; k0 < DIM; k0 += 16) {
        {
            const int m = m0 + lr;
            float4 a = make_float4(0.f,0.f,0.f,0.f);
            if (m < M) a = *(const float4*)(A + (size_t)m*DIM + k0 + lk4);
            As[lk4+0][lr]=a.x; As[lk4+1][lr]=a.y; As[lk4+2][lr]=a.z; As[lk4+3][lr]=a.w;
        }
        {
            const float4 w = *(const float4*)(W + (size_t)(j0+lr)*DIM + k0 + lk4);
            Bs[lk4+0][lr]=w.x; Bs[lk4+1][lr]=w.y; Bs[lk4+2][lr]=w.z; Bs[lk4+3][lr]=w.w;
        }
        __syncthreads();
        #pragma unroll
        for (int kk = 0; kk < 16; ++kk) {
            float a[4] = {As[kk][ty], As[kk][ty+16], As[kk][ty+32], As[kk][ty+48]};
            float b[4] = {Bs[kk][tx], Bs[kk][tx+16], Bs[kk][tx+32], Bs[kk][tx+48]};
            #pragma unroll
            for (int i = 0; i < 4; ++i)
                #pragma unroll
                for (int j = 0; j < 4; ++j)
                    acc[i][j] += a[i]*b[j];
        }
        __syncthreads();
    }
    #pragma unroll
    for (int i = 0; i < 4; ++i) {
        const int m = m0 + ty + 16*i;
        if (m >= M) continue;
        const float f = rowscale ? rowscale[m] : 1.f;
        #pragma unroll
        for (int jj = 0; jj < 4; ++jj) {
            const int j = j0 + tx + 16*jj;
            out[(size_t)m*DIM + j] = acc[i][jj] + f*bias[j];
        }
    }
}

// ---------------------------------------------------------------------------
extern "C" void kernel_launch(void* const* d_in, const int* in_sizes, int n_in,
                              void* d_out, int out_size, void* d_ws, size_t ws_size,
                              hipStream_t stream)
{
    const float* queries = (const float*)d_in[0];
    const float* pos_emb = (const float*)d_in[1];
    const float* lvl_emb = (const float*)d_in[2];
    const float* cam_emb = (const float*)d_in[3];
    const float* features= (const float*)d_in[4];
    const float* ref3d   = (const float*)d_in[5];
    const int*   bev     = (const int*)d_in[6];
    const float* Wv = (const float*)d_in[7];
    const float* bv = (const float*)d_in[8];
    const float* Wo = (const float*)d_in[9];
    const float* bo = (const float*)d_in[10];
    const float* Wa = (const float*)d_in[11];
    const float* ba = (const float*)d_in[12];
    const float* Wi = (const float*)d_in[13];
    const float* bi = (const float*)d_in[14];
    const float* Wz = (const float*)d_in[15];
    const float* bz = (const float*)d_in[16];
    float* out = (float*)d_out;

    float* ws = (float*)d_ws;
    size_t o = 0;
    float* value_t  = ws + o; o += (size_t)BN*HEADS*HW_*HDD;   //  4,325,376
    float* off_ws   = ws + o; o += (size_t)MTOT*128;           //  7,680,000
    float* attw_ws  = ws + o; o += (size_t)MTOT*64;            //  3,840,000
    float* combined = ws + o; o += (size_t)MTOT*DIM;           // 15,360,000
    float* asum     = ws + o; o += (size_t)NQ*DIM;             //  2,560,000
    float* slots    = ws + o; o += (size_t)NQ*DIM;             //  2,560,000
    float* biasf    = ws + o; o += NQ;                         //     10,000
    float* ebias    = ws + o; o += BN*DIM;                     //      1,536
    // total ~145.4 MB

    k_ebias  <<<BN, 256, 0, stream>>>(lvl_emb, cam_emb, Wv, bv, ebias);
    k_value  <<<dim3(HW_/64, DIM/64, BN), 256, 0, stream>>>(features, Wv, ebias, value_t);
    k_offattn<<<dim3((MTOT+63)/64, 3), 256, 0, stream>>>(queries, pos_emb, Wo, bo, Wa, ba, off_ws, attw_ws);
    k_sample <<<dim3((NQ+31)/32, BN), 256, 0, stream>>>(value_t, off_ws, attw_ws, ref3d, combined);
    k_reduce <<<NQ, 256, 0, stream>>>(combined, bev, asum, biasf);
    k_gemm_nb<<<dim3((NQ+63)/64, DIM/64), 256, 0, stream>>>(asum, Wi, bi, biasf, slots, NQ);
    k_gemm_nb<<<dim3((NQ+63)/64, DIM/64), 256, 0, stream>>>(slots, Wz, bz, nullptr, out, NQ);
}

// Round 2
// 487.102 us; speedup vs baseline: 1.4743x; 1.4743x over previous
//
#include <hip/hip_runtime.h>
#include <hip/hip_bf16.h>

#define BN     6
#define NQ     10000
#define DIM    256
#define HEADS  8
#define HDD    32
#define HF_    32
#define WF_    88
#define HW_    (HF_*WF_)     /* 2816 */
#define MTOT   (BN*NQ)       /* 60000 */

typedef __attribute__((ext_vector_type(8))) unsigned short ushort8_t;

// ---------------------------------------------------------------------------
// K0: ebias[n][j] = sum_d (lvl[d]+cam[n][d]) * W_value[j][d] + b_value[j]
// ---------------------------------------------------------------------------
__global__ __launch_bounds__(256)
void k_ebias(const float* __restrict__ lvl, const float* __restrict__ cam,
             const float* __restrict__ Wv, const float* __restrict__ bv,
             float* __restrict__ ebias)
{
    const int n = blockIdx.x;
    const int j = threadIdx.x;
    __shared__ float e[DIM];
    e[j] = lvl[j] + cam[n*DIM + j];
    __syncthreads();
    const float* w = Wv + (size_t)j*DIM;
    float s = bv[j];
    for (int d = 0; d < DIM; ++d) s += e[d]*w[d];
    ebias[n*DIM + j] = s;
}

// ---------------------------------------------------------------------------
// K1: value_bf[n][h][p][c] = bf16( sum_d feat[n][d][p]*Wv[h*32+c][d] + ebias )
// 64p x 64j tile, K=256 in chunks of 16, 4x4 microtile.
// ---------------------------------------------------------------------------
__global__ __launch_bounds__(256)
void k_value(const float* __restrict__ feat, const float* __restrict__ Wv,
             const float* __restrict__ ebias, __hip_bfloat16* __restrict__ value_bf)
{
    const int n  = blockIdx.z;
    const int p0 = blockIdx.x * 64;
    const int j0 = blockIdx.y * 64;
    const int tid = threadIdx.x;
    const int tx = tid & 15, ty = tid >> 4;
    __shared__ float As[16][65];
    __shared__ float Bs[16][65];
    float acc[4][4] = {};
    const int ak  = tid >> 4;
    const int ap4 = (tid & 15) * 4;
    const int bj  = tid >> 2;
    const int bk4 = (tid & 3) * 4;

    for (int k0 = 0; k0 < DIM; k0 += 16) {
        {
            const float4 v = *(const float4*)(feat + (size_t)(n*DIM + k0 + ak)*HW_ + p0 + ap4);
            As[ak][ap4+0]=v.x; As[ak][ap4+1]=v.y; As[ak][ap4+2]=v.z; As[ak][ap4+3]=v.w;
        }
        {
            const float4 w = *(const float4*)(Wv + (size_t)(j0 + bj)*DIM + k0 + bk4);
            Bs[bk4+0][bj]=w.x; Bs[bk4+1][bj]=w.y; Bs[bk4+2][bj]=w.z; Bs[bk4+3][bj]=w.w;
        }
        __syncthreads();
        #pragma unroll
        for (int kk = 0; kk < 16; ++kk) {
            float a[4] = {As[kk][ty], As[kk][ty+16], As[kk][ty+32], As[kk][ty+48]};
            float b[4] = {Bs[kk][tx], Bs[kk][tx+16], Bs[kk][tx+32], Bs[kk][tx+48]};
            #pragma unroll
            for (int i = 0; i < 4; ++i)
                #pragma unroll
                for (int j = 0; j < 4; ++j)
                    acc[i][j] += a[i]*b[j];
        }
        __syncthreads();
    }
    #pragma unroll
    for (int i = 0; i < 4; ++i) {
        const int p = p0 + ty + 16*i;
        #pragma unroll
        for (int jj = 0; jj < 4; ++jj) {
            const int jc = j0 + tx + 16*jj;
            const int h = jc >> 5, c = jc & 31;
            value_bf[((size_t)(n*HEADS + h)*HW_ + p)*HDD + c] =
                __float2bfloat16(acc[i][jj] + ebias[n*DIM + jc]);
        }
    }
}

// ---------------------------------------------------------------------------
// K2a: off/attn-logit GEMM (unchanged)
// ---------------------------------------------------------------------------
__global__ __launch_bounds__(256)
void k_offattn(const float* __restrict__ Qr, const float* __restrict__ Pe,
               const float* __restrict__ Woff, const float* __restrict__ boff,
               const float* __restrict__ Wattn, const float* __restrict__ battn,
               float* __restrict__ off_ws, float* __restrict__ attw_ws)
{
    const int m0 = blockIdx.x * 64;
    const int j0 = blockIdx.y * 64;
    const int tid = threadIdx.x;
    const int tx = tid & 15, ty = tid >> 4;
    __shared__ float As[16][65];
    __shared__ float Bs[16][65];
    float acc[4][4] = {};
    const int lr  = tid >> 2;
    const int lk4 = (tid & 3) * 4;

    for (int k0 = 0; k0 < DIM; k0 += 16) {
        {
            const int m = m0 + lr;
            float4 a = make_float4(0.f,0.f,0.f,0.f);
            if (m < MTOT) {
                const float4 x = *(const float4*)(Qr + (size_t)m*DIM + k0 + lk4);
                const float4 y = *(const float4*)(Pe + (size_t)m*DIM + k0 + lk4);
                a = make_float4(x.x+y.x, x.y+y.y, x.z+y.z, x.w+y.w);
            }
            As[lk4+0][lr]=a.x; As[lk4+1][lr]=a.y; As[lk4+2][lr]=a.z; As[lk4+3][lr]=a.w;
        }
        {
            const int j = j0 + lr;
            const float* Wrow = (j < 128) ? (Woff + (size_t)j*DIM) : (Wattn + (size_t)(j-128)*DIM);
            const float4 w = *(const float4*)(Wrow + k0 + lk4);
            Bs[lk4+0][lr]=w.x; Bs[lk4+1][lr]=w.y; Bs[lk4+2][lr]=w.z; Bs[lk4+3][lr]=w.w;
        }
        __syncthreads();
        #pragma unroll
        for (int kk = 0; kk < 16; ++kk) {
            float a[4] = {As[kk][ty], As[kk][ty+16], As[kk][ty+32], As[kk][ty+48]};
            float b[4] = {Bs[kk][tx], Bs[kk][tx+16], Bs[kk][tx+32], Bs[kk][tx+48]};
            #pragma unroll
            for (int i = 0; i < 4; ++i)
                #pragma unroll
                for (int j = 0; j < 4; ++j)
                    acc[i][j] += a[i]*b[j];
        }
        __syncthreads();
    }
    #pragma unroll
    for (int i = 0; i < 4; ++i) {
        const int m = m0 + ty + 16*i;
        if (m >= MTOT) continue;
        #pragma unroll
        for (int jj = 0; jj < 4; ++jj) {
            const int j = j0 + tx + 16*jj;
            const float v = acc[i][jj];
            if (j < 128) off_ws [(size_t)m*128 + j]       = v + boff[j];
            else         attw_ws[(size_t)m*64  + (j-128)] = v + battn[j-128];
        }
    }
}

// ---------------------------------------------------------------------------
// K2b: sampling, rewritten. thread = (q-in-8, head, channel-quarter).
// 8 channels/thread; branchless clamped gathers from bf16 value rows;
// off/attw/ref staged in LDS per block.
// ---------------------------------------------------------------------------
__global__ __launch_bounds__(256)
void k_sample(const __hip_bfloat16* __restrict__ value_bf,
              const float* __restrict__ off_ws, const float* __restrict__ attw_ws,
              const float* __restrict__ ref3d, float* __restrict__ combined)
{
    const int n  = blockIdx.y;
    const int q0 = blockIdx.x * 8;
    const int tid = threadIdx.x;

    __shared__ float s_off[8][128];
    __shared__ float s_att[8][64];
    __shared__ float s_ref[8][8];
    {
        const float4* so = (const float4*)(off_ws + ((size_t)n*NQ + q0)*128);
        ((float4*)&s_off[0][0])[tid] = so[tid];                 // 1024 floats
        const float2* sa = (const float2*)(attw_ws + ((size_t)n*NQ + q0)*64);
        ((float2*)&s_att[0][0])[tid] = sa[tid];                 // 512 floats
        if (tid < 64)
            (&s_ref[0][0])[tid] = (ref3d + ((size_t)n*NQ + q0)*8)[tid];
    }
    __syncthreads();

    const int quarter = tid & 3;
    const int h  = (tid >> 2) & 7;
    const int ql = tid >> 5;
    const int q  = q0 + ql;

    // softmax over this head's 8 logits (redundant x4 across quarters — VALU is idle)
    float lg[8];
    float mx = -1e30f;
    #pragma unroll
    for (int p = 0; p < 8; ++p) { lg[p] = s_att[ql][h*8+p]; mx = fmaxf(mx, lg[p]); }
    float ssum = 0.f;
    #pragma unroll
    for (int p = 0; p < 8; ++p) { lg[p] = __expf(lg[p]-mx); ssum += lg[p]; }
    const float inv = 1.f/ssum;

    const unsigned short* vbase =
        (const unsigned short*)value_bf + (size_t)(n*HEADS + h)*HW_*HDD + quarter*8;

    float acc[8];
    #pragma unroll
    for (int c = 0; c < 8; ++c) acc[c] = 0.f;

    #pragma unroll
    for (int p = 0; p < 8; ++p) {
        const int z = p & 3;                         // off_z reshape: p = j*4+z
        const float ax = s_ref[ql][z*2+0]*WF_ + s_off[ql][h*16+p*2+0] - 0.5f;
        const float ay = s_ref[ql][z*2+1]*HF_ + s_off[ql][h*16+p*2+1] - 0.5f;
        const float fx = floorf(ax), fy = floorf(ay);
        const float dx = ax-fx, dy = ay-fy;
        const int x0 = (int)fx, y0 = (int)fy;
        const float wp = lg[p]*inv;
        #pragma unroll
        for (int oy = 0; oy < 2; ++oy) {
            const int yi = y0 + oy;
            const float wy = oy ? dy : 1.f-dy;
            #pragma unroll
            for (int ox = 0; ox < 2; ++ox) {
                const int xi = x0 + ox;
                const float wx = ox ? dx : 1.f-dx;
                const bool valid = ((unsigned)xi < WF_) & ((unsigned)yi < HF_);
                const float cw = valid ? wp*wy*wx : 0.f;
                const int xc = min(max(xi, 0), WF_-1);
                const int yc = min(max(yi, 0), HF_-1);
                const ushort8_t v = *(const ushort8_t*)(vbase + (size_t)(yc*WF_ + xc)*HDD);
                #pragma unroll
                for (int c = 0; c < 8; ++c)
                    acc[c] += cw * __uint_as_float(((unsigned)v[c]) << 16);
            }
        }
    }

    float4* outp = (float4*)(combined + ((size_t)n*NQ + q)*DIM + h*HDD + quarter*8);
    outp[0] = make_float4(acc[0], acc[1], acc[2], acc[3]);
    outp[1] = make_float4(acc[4], acc[5], acc[6], acc[7]);
}

// ---------------------------------------------------------------------------
// K3a: camera reduce (unchanged)
// ---------------------------------------------------------------------------
__global__ __launch_bounds__(256)
void k_reduce(const float* __restrict__ combined, const int* __restrict__ bev_mask,
              float* __restrict__ asum, float* __restrict__ biasf)
{
    const int q = blockIdx.x;
    const int d = threadIdx.x;
    __shared__ float s_hit[BN];
    __shared__ float s_scale, s_bias;
    if (d < BN) {
        int hit = 0;
        #pragma unroll
        for (int z = 0; z < 4; ++z)
            hit |= (bev_mask[(((size_t)d*NQ + q)*4 + z)*2] != 0);
        s_hit[d] = (float)hit;
    }
    __syncthreads();
    if (d == 0) {
        float c = 0.f;
        for (int nn = 0; nn < BN; ++nn) c += s_hit[nn];
        s_bias  = (c > 0.f) ? 1.f : 0.f;
        s_scale = 1.f / fmaxf(c, 1.f);
    }
    __syncthreads();
    float a = 0.f;
    for (int nn = 0; nn < BN; ++nn)
        a += s_hit[nn] * combined[((size_t)nn*NQ + q)*DIM + d];
    asum[(size_t)q*DIM + d] = a * s_scale;
    if (d == 0) biasf[q] = s_bias;
}

// ---------------------------------------------------------------------------
// K3b/K4: generic 64x64-tiled GEMM (unchanged)
// ---------------------------------------------------------------------------
__global__ __launch_bounds__(256)
void k_gemm_nb(const float* __restrict__ A, const float* __restrict__ W,
               const float* __restrict__ bias, const float* __restrict__ rowscale,
               float* __restrict__ out, int M)
{
    const int m0 = blockIdx.x * 64;
    const int j0 = blockIdx.y * 64;
    const int tid = threadIdx.x;
    const int tx = tid & 15, ty = tid >> 4;
    __shared__ float As[16][65];
    __shared__ float Bs[16][65];
    float acc[4][4] = {};
    const int lr  = tid >> 2;
    const int lk4 = (tid & 3) * 4;

    for (int k0 = 0; k0 < DIM; k0 += 16) {
        {
            const int m = m0 + lr;
            float4 a = make_float4(0.f,0.f,0.f,0.f);
            if (m < M) a = *(const float4*)(A + (size_t)m*DIM + k0 + lk4);
            As[lk4+0][lr]=a.x; As[lk4+1][lr]=a.y; As[lk4+2][lr]=a.z; As[lk4+3][lr]=a.w;
        }
        {
            const float4 w = *(const float4*)(W + (size_t)(j0+lr)*DIM + k0 + lk4);
            Bs[lk4+0][lr]=w.x; Bs[lk4+1][lr]=w.y; Bs[lk4+2][lr]=w.z; Bs[lk4+3][lr]=w.w;
        }
        __syncthreads();
        #pragma unroll
        for (int kk = 0; kk < 16; ++kk) {
            float a[4] = {As[kk][ty], As[kk][ty+16], As[kk][ty+32], As[kk][ty+48]};
            float b[4] = {Bs[kk][tx], Bs[kk][tx+16], Bs[kk][tx+32], Bs[kk][tx+48]};
            #pragma unroll
            for (int i = 0; i < 4; ++i)
                #pragma unroll
                for (int j = 0; j < 4; ++j)
                    acc[i][j] += a[i]*b[j];
        }
        __syncthreads();
    }
    #pragma unroll
    for (int i = 0; i < 4; ++i) {
        const int m = m0 + ty + 16*i;
        if (m >= M) continue;
        const float f = rowscale ? rowscale[m] : 1.f;
        #pragma unroll
        for (int jj = 0; jj < 4; ++jj) {
            const int j = j0 + tx + 16*jj;
            out[(size_t)m*DIM + j] = acc[i][jj] + f*bias[j];
        }
    }
}

// ---------------------------------------------------------------------------
extern "C" void kernel_launch(void* const* d_in, const int* in_sizes, int n_in,
                              void* d_out, int out_size, void* d_ws, size_t ws_size,
                              hipStream_t stream)
{
    const float* queries = (const float*)d_in[0];
    const float* pos_emb = (const float*)d_in[1];
    const float* lvl_emb = (const float*)d_in[2];
    const float* cam_emb = (const float*)d_in[3];
    const float* features= (const float*)d_in[4];
    const float* ref3d   = (const float*)d_in[5];
    const int*   bev     = (const int*)d_in[6];
    const float* Wv = (const float*)d_in[7];
    const float* bv = (const float*)d_in[8];
    const float* Wo = (const float*)d_in[9];
    const float* bo = (const float*)d_in[10];
    const float* Wa = (const float*)d_in[11];
    const float* ba = (const float*)d_in[12];
    const float* Wi = (const float*)d_in[13];
    const float* bi = (const float*)d_in[14];
    const float* Wz = (const float*)d_in[15];
    const float* bz = (const float*)d_in[16];
    float* out = (float*)d_out;

    float* ws = (float*)d_ws;
    size_t o = 0;
    __hip_bfloat16* value_bf = (__hip_bfloat16*)(ws + o);
    o += (size_t)BN*HEADS*HW_*HDD/2;                           //  2,162,688 floats (bf16 x 4.3M)
    float* off_ws   = ws + o; o += (size_t)MTOT*128;           //  7,680,000
    float* attw_ws  = ws + o; o += (size_t)MTOT*64;            //  3,840,000
    float* combined = ws + o; o += (size_t)MTOT*DIM;           // 15,360,000
    float* asum     = ws + o; o += (size_t)NQ*DIM;             //  2,560,000
    float* slots    = ws + o; o += (size_t)NQ*DIM;             //  2,560,000
    float* biasf    = ws + o; o += NQ;                         //     10,000
    float* ebias    = ws + o; o += BN*DIM;                     //      1,536

    k_ebias  <<<BN, 256, 0, stream>>>(lvl_emb, cam_emb, Wv, bv, ebias);
    k_value  <<<dim3(HW_/64, DIM/64, BN), 256, 0, stream>>>(features, Wv, ebias, value_bf);
    k_offattn<<<dim3((MTOT+63)/64, 3), 256, 0, stream>>>(queries, pos_emb, Wo, bo, Wa, ba, off_ws, attw_ws);
    k_sample <<<dim3(NQ/8, BN), 256, 0, stream>>>(value_bf, off_ws, attw_ws, ref3d, combined);
    k_reduce <<<NQ, 256, 0, stream>>>(combined, bev, asum, biasf);
    k_gemm_nb<<<dim3((NQ+63)/64, DIM/64), 256, 0, stream>>>(asum, Wi, bi, biasf, slots, NQ);
    k_gemm_nb<<<dim3((NQ+63)/64, DIM/64), 256, 0, stream>>>(slots, Wz, bz, nullptr, out, NQ);
}

// Round 3
// 446.228 us; speedup vs baseline: 1.6094x; 1.0916x over previous
//
#include <hip/hip_runtime.h>
#include <hip/hip_bf16.h>

#define BN     6
#define NQ     10000
#define DIM    256
#define HEADS  8
#define HDD    32
#define HF_    32
#define WF_    88
#define HW_    (HF_*WF_)     /* 2816 */
#define MTOT   (BN*NQ)       /* 60000 */

typedef __attribute__((ext_vector_type(8))) unsigned short ushort8_t;

static __device__ inline unsigned short f2bf(float x) {
    __hip_bfloat16 b = __float2bfloat16(x);
    return *(unsigned short*)&b;
}

// ---------------------------------------------------------------------------
// K0: ebias[n][j] = sum_d (lvl[d]+cam[n][d]) * W_value[j][d] + b_value[j]
// ---------------------------------------------------------------------------
__global__ __launch_bounds__(256)
void k_ebias(const float* __restrict__ lvl, const float* __restrict__ cam,
             const float* __restrict__ Wv, const float* __restrict__ bv,
             float* __restrict__ ebias)
{
    const int n = blockIdx.x;
    const int j = threadIdx.x;
    __shared__ float e[DIM];
    e[j] = lvl[j] + cam[n*DIM + j];
    __syncthreads();
    const float* w = Wv + (size_t)j*DIM;
    float s = bv[j];
    for (int d = 0; d < DIM; ++d) s += e[d]*w[d];
    ebias[n*DIM + j] = s;
}

// ---------------------------------------------------------------------------
// K_mask: per-q hit flags, count scale, bias gate.
// ---------------------------------------------------------------------------
__global__ __launch_bounds__(256)
void k_mask(const int* __restrict__ bev, float* __restrict__ hitf,
            float* __restrict__ scale, float* __restrict__ biasf)
{
    const int q = blockIdx.x*256 + threadIdx.x;
    if (q >= NQ) return;
    float cnt = 0.f;
    #pragma unroll
    for (int n = 0; n < BN; ++n) {
        int hit = 0;
        #pragma unroll
        for (int z = 0; z < 4; ++z)
            hit |= (bev[(((size_t)n*NQ + q)*4 + z)*2] != 0);
        hitf[(size_t)n*NQ + q] = (float)hit;
        cnt += (float)hit;
    }
    biasf[q] = (cnt > 0.f) ? 1.f : 0.f;
    scale[q] = 1.f / fmaxf(cnt, 1.f);
}

// ---------------------------------------------------------------------------
// K1: value_bf[n][h][p][c] = bf16( sum_d feat[n][d][p]*Wv[h*32+c][d] + ebias )
// 64p x 64j tile, 4x4 microtile with float4 LDS fragments.
// ---------------------------------------------------------------------------
__global__ __launch_bounds__(256)
void k_value(const float* __restrict__ feat, const float* __restrict__ Wv,
             const float* __restrict__ ebias, __hip_bfloat16* __restrict__ value_bf)
{
    const int n  = blockIdx.z;
    const int p0 = blockIdx.x * 64;
    const int j0 = blockIdx.y * 64;
    const int tid = threadIdx.x;
    const int tx = tid & 15, ty = tid >> 4;
    __shared__ float As[16][68];
    __shared__ float Bs[16][68];
    float acc[4][4] = {};
    const int ak  = tid >> 4;          // k row for A load
    const int ap4 = (tid & 15) * 4;    // p offset (float4)
    const int bj  = tid >> 2;          // j row for B load
    const int bk4 = (tid & 3) * 4;     // k offset (float4)

    for (int k0 = 0; k0 < DIM; k0 += 16) {
        {
            const float4 v = *(const float4*)(feat + (size_t)(n*DIM + k0 + ak)*HW_ + p0 + ap4);
            *(float4*)&As[ak][ap4] = v;   // feat is k-major: contiguous LDS store
        }
        {
            const float4 w = *(const float4*)(Wv + (size_t)(j0 + bj)*DIM + k0 + bk4);
            Bs[bk4+0][bj]=w.x; Bs[bk4+1][bj]=w.y; Bs[bk4+2][bj]=w.z; Bs[bk4+3][bj]=w.w;
        }
        __syncthreads();
        #pragma unroll
        for (int kk = 0; kk < 16; ++kk) {
            const float4 a4 = *(const float4*)&As[kk][ty*4];
            const float4 b4 = *(const float4*)&Bs[kk][tx*4];
            const float a[4] = {a4.x, a4.y, a4.z, a4.w};
            const float b[4] = {b4.x, b4.y, b4.z, b4.w};
            #pragma unroll
            for (int i = 0; i < 4; ++i)
                #pragma unroll
                for (int j = 0; j < 4; ++j)
                    acc[i][j] += a[i]*b[j];
        }
        __syncthreads();
    }
    const int jc0 = j0 + tx*4;
    const int h = jc0 >> 5, c0 = jc0 & 31;
    const float eb[4] = {ebias[n*DIM+jc0], ebias[n*DIM+jc0+1], ebias[n*DIM+jc0+2], ebias[n*DIM+jc0+3]};
    #pragma unroll
    for (int i = 0; i < 4; ++i) {
        const int p = p0 + ty*4 + i;
        ushort4 pk;
        pk.x = f2bf(acc[i][0] + eb[0]);
        pk.y = f2bf(acc[i][1] + eb[1]);
        pk.z = f2bf(acc[i][2] + eb[2]);
        pk.w = f2bf(acc[i][3] + eb[3]);
        *(ushort4*)((unsigned short*)value_bf + ((size_t)(n*HEADS + h)*HW_ + p)*HDD + c0) = pk;
    }
}

// ---------------------------------------------------------------------------
// K2a: off/attn GEMM, single pass over all 192 cols. 64 rows/block,
// microtile 4m x 12n, float4 LDS fragments.
// ---------------------------------------------------------------------------
__global__ __launch_bounds__(256)
void k_offattn(const float* __restrict__ Qr, const float* __restrict__ Pe,
               const float* __restrict__ Woff, const float* __restrict__ boff,
               const float* __restrict__ Wattn, const float* __restrict__ battn,
               float* __restrict__ off_ws, float* __restrict__ attw_ws)
{
    const int m0 = blockIdx.x * 64;
    const int tid = threadIdx.x;
    const int tn = tid & 15;      // 12 cols each
    const int tm = tid >> 4;      // 4 rows each
    __shared__ float As[16][68];
    __shared__ float Bs[16][200];
    float acc[4][12] = {};
    const int lr  = tid >> 2;        // 0..63
    const int lk4 = (tid & 3) * 4;   // 0,4,8,12

    for (int k0 = 0; k0 < DIM; k0 += 16) {
        {
            const int m = m0 + lr;
            float4 a = make_float4(0.f,0.f,0.f,0.f);
            if (m < MTOT) {
                const float4 x = *(const float4*)(Qr + (size_t)m*DIM + k0 + lk4);
                const float4 y = *(const float4*)(Pe + (size_t)m*DIM + k0 + lk4);
                a = make_float4(x.x+y.x, x.y+y.y, x.z+y.z, x.w+y.w);
            }
            As[lk4+0][lr]=a.x; As[lk4+1][lr]=a.y; As[lk4+2][lr]=a.z; As[lk4+3][lr]=a.w;
        }
        #pragma unroll
        for (int i = 0; i < 3; ++i) {
            const int row = i*64 + lr;
            const float* Wrow = (row < 128) ? (Woff + (size_t)row*DIM)
                                            : (Wattn + (size_t)(row-128)*DIM);
            const float4 w = *(const float4*)(Wrow + k0 + lk4);
            Bs[lk4+0][row]=w.x; Bs[lk4+1][row]=w.y; Bs[lk4+2][row]=w.z; Bs[lk4+3][row]=w.w;
        }
        __syncthreads();
        #pragma unroll
        for (int kk = 0; kk < 16; ++kk) {
            const float4 a4 = *(const float4*)&As[kk][tm*4];
            const float4 b0 = *(const float4*)&Bs[kk][tn*12];
            const float4 b1 = *(const float4*)&Bs[kk][tn*12+4];
            const float4 b2 = *(const float4*)&Bs[kk][tn*12+8];
            const float a[4]  = {a4.x,a4.y,a4.z,a4.w};
            const float b[12] = {b0.x,b0.y,b0.z,b0.w, b1.x,b1.y,b1.z,b1.w, b2.x,b2.y,b2.z,b2.w};
            #pragma unroll
            for (int i = 0; i < 4; ++i)
                #pragma unroll
                for (int j = 0; j < 12; ++j)
                    acc[i][j] += a[i]*b[j];
        }
        __syncthreads();
    }
    #pragma unroll
    for (int i = 0; i < 4; ++i) {
        const int m = m0 + tm*4 + i;
        if (m >= MTOT) continue;
        #pragma unroll
        for (int j = 0; j < 12; ++j) {
            const int col = tn*12 + j;
            const float v = acc[i][j];
            if (col < 128) off_ws [(size_t)m*128 + col]         = v + boff[col];
            else           attw_ws[(size_t)m*64  + (col-128)]   = v + battn[col-128];
        }
    }
}

// ---------------------------------------------------------------------------
// K2b: sampling fused with camera reduce. Block = 8 queries, all 6 cameras.
// thread = (q-in-8, head, channel-quarter); writes asum directly.
// ---------------------------------------------------------------------------
__global__ __launch_bounds__(256)
void k_sample(const __hip_bfloat16* __restrict__ value_bf,
              const float* __restrict__ off_ws, const float* __restrict__ attw_ws,
              const float* __restrict__ ref3d, const float* __restrict__ hitf,
              const float* __restrict__ scale, float* __restrict__ asum)
{
    const int q0 = blockIdx.x * 8;
    const int tid = threadIdx.x;

    __shared__ float s_off[8][128];
    __shared__ float s_att[8][64];
    __shared__ float s_ref[8][8];
    __shared__ float s_hit[BN][8];
    __shared__ float s_scl[8];

    if (tid < 48) s_hit[tid>>3][tid&7] = hitf[(size_t)(tid>>3)*NQ + q0 + (tid&7)];
    if (tid < 8)  s_scl[tid] = scale[q0 + tid];

    const int quarter = tid & 3;
    const int h  = (tid >> 2) & 7;
    const int ql = tid >> 5;

    float acc[8];
    #pragma unroll
    for (int c = 0; c < 8; ++c) acc[c] = 0.f;

    for (int n = 0; n < BN; ++n) {
        __syncthreads();   // WAR: previous iteration done reading staging
        {
            const float4* so = (const float4*)(off_ws + ((size_t)n*NQ + q0)*128);
            ((float4*)&s_off[0][0])[tid] = so[tid];
            const float2* sa = (const float2*)(attw_ws + ((size_t)n*NQ + q0)*64);
            ((float2*)&s_att[0][0])[tid] = sa[tid];
            if (tid < 64)
                (&s_ref[0][0])[tid] = (ref3d + ((size_t)n*NQ + q0)*8)[tid];
        }
        __syncthreads();

        if (s_hit[n][ql] != 0.f) {
            // softmax over this head's 8 logits
            float lg[8];
            float mx = -1e30f;
            #pragma unroll
            for (int p = 0; p < 8; ++p) { lg[p] = s_att[ql][h*8+p]; mx = fmaxf(mx, lg[p]); }
            float ssum = 0.f;
            #pragma unroll
            for (int p = 0; p < 8; ++p) { lg[p] = __expf(lg[p]-mx); ssum += lg[p]; }
            const float inv = 1.f/ssum;

            const unsigned short* vbase =
                (const unsigned short*)value_bf + (size_t)(n*HEADS + h)*HW_*HDD + quarter*8;

            #pragma unroll
            for (int p = 0; p < 8; ++p) {
                const int z = p & 3;                 // off_z reshape: p = j*4+z
                const float ax = s_ref[ql][z*2+0]*WF_ + s_off[ql][h*16+p*2+0] - 0.5f;
                const float ay = s_ref[ql][z*2+1]*HF_ + s_off[ql][h*16+p*2+1] - 0.5f;
                const float fx = floorf(ax), fy = floorf(ay);
                const float dx = ax-fx, dy = ay-fy;
                const int x0 = (int)fx, y0 = (int)fy;
                const float wp = lg[p]*inv;
                #pragma unroll
                for (int oy = 0; oy < 2; ++oy) {
                    const int yi = y0 + oy;
                    const float wy = oy ? dy : 1.f-dy;
                    #pragma unroll
                    for (int ox = 0; ox < 2; ++ox) {
                        const int xi = x0 + ox;
                        const float wx = ox ? dx : 1.f-dx;
                        const bool valid = ((unsigned)xi < WF_) & ((unsigned)yi < HF_);
                        const float cw = valid ? wp*wy*wx : 0.f;
                        const int xc = min(max(xi, 0), WF_-1);
                        const int yc = min(max(yi, 0), HF_-1);
                        const ushort8_t v = *(const ushort8_t*)(vbase + (size_t)(yc*WF_ + xc)*HDD);
                        #pragma unroll
                        for (int c = 0; c < 8; ++c)
                            acc[c] += cw * __uint_as_float(((unsigned)v[c]) << 16);
                    }
                }
            }
        }
    }

    const float sc = s_scl[ql];
    float4* outp = (float4*)(asum + ((size_t)(q0+ql))*DIM + h*HDD + quarter*8);
    outp[0] = make_float4(acc[0]*sc, acc[1]*sc, acc[2]*sc, acc[3]*sc);
    outp[1] = make_float4(acc[4]*sc, acc[5]*sc, acc[6]*sc, acc[7]*sc);
}

// ---------------------------------------------------------------------------
// K3/K4: 64x64-tiled GEMM, 4x4 microtile with float4 LDS fragments.
// out[m][j] = A[m]·W[j] + f(m)*bias[j]; rowscale==nullptr -> f=1.
// ---------------------------------------------------------------------------
__global__ __launch_bounds__(256)
void k_gemm_nb(const float* __restrict__ A, const float* __restrict__ W,
               const float* __restrict__ bias, const float* __restrict__ rowscale,
               float* __restrict__ out, int M)
{
    const int m0 = blockIdx.x * 64;
    const int j0 = blockIdx.y * 64;
    const int tid = threadIdx.x;
    const int tx = tid & 15, ty = tid >> 4;
    __shared__ float As[16][68];
    __shared__ float Bs[16][68];
    float acc[4][4] = {};
    const int lr  = tid >> 2;
    const int lk4 = (tid & 3) * 4;

    for (int k0 = 0; k0 < DIM; k0 += 16) {
        {
            const int m = m0 + lr;
            float4 a = make_float4(0.f,0.f,0.f,0.f);
            if (m < M) a = *(const float4*)(A + (size_t)m*DIM + k0 + lk4);
            As[lk4+0][lr]=a.x; As[lk4+1][lr]=a.y; As[lk4+2][lr]=a.z; As[lk4+3][lr]=a.w;
        }
        {
            const float4 w = *(const float4*)(W + (size_t)(j0+lr)*DIM + k0 + lk4);
            Bs[lk4+0][lr]=w.x; Bs[lk4+1][lr]=w.y; Bs[lk4+2][lr]=w.z; Bs[lk4+3][lr]=w.w;
        }
        __syncthreads();
        #pragma unroll
        for (int kk = 0; kk < 16; ++kk) {
            const float4 a4 = *(const float4*)&As[kk][ty*4];
            const float4 b4 = *(const float4*)&Bs[kk][tx*4];
            const float a[4] = {a4.x, a4.y, a4.z, a4.w};
            const float b[4] = {b4.x, b4.y, b4.z, b4.w};
            #pragma unroll
            for (int i = 0; i < 4; ++i)
                #pragma unroll
                for (int j = 0; j < 4; ++j)
                    acc[i][j] += a[i]*b[j];
        }
        __syncthreads();
    }
    const float4 bv = *(const float4*)&bias[j0 + tx*4];
    #pragma unroll
    for (int i = 0; i < 4; ++i) {
        const int m = m0 + ty*4 + i;
        if (m >= M) continue;
        const float f = rowscale ? rowscale[m] : 1.f;
        float4 o;
        o.x = acc[i][0] + f*bv.x;
        o.y = acc[i][1] + f*bv.y;
        o.z = acc[i][2] + f*bv.z;
        o.w = acc[i][3] + f*bv.w;
        *(float4*)&out[(size_t)m*DIM + j0 + tx*4] = o;
    }
}

// ---------------------------------------------------------------------------
extern "C" void kernel_launch(void* const* d_in, const int* in_sizes, int n_in,
                              void* d_out, int out_size, void* d_ws, size_t ws_size,
                              hipStream_t stream)
{
    const float* queries = (const float*)d_in[0];
    const float* pos_emb = (const float*)d_in[1];
    const float* lvl_emb = (const float*)d_in[2];
    const float* cam_emb = (const float*)d_in[3];
    const float* features= (const float*)d_in[4];
    const float* ref3d   = (const float*)d_in[5];
    const int*   bev     = (const int*)d_in[6];
    const float* Wv = (const float*)d_in[7];
    const float* bv = (const float*)d_in[8];
    const float* Wo = (const float*)d_in[9];
    const float* bo = (const float*)d_in[10];
    const float* Wa = (const float*)d_in[11];
    const float* ba = (const float*)d_in[12];
    const float* Wi = (const float*)d_in[13];
    const float* bi = (const float*)d_in[14];
    const float* Wz = (const float*)d_in[15];
    const float* bz = (const float*)d_in[16];
    float* out = (float*)d_out;

    float* ws = (float*)d_ws;
    size_t o = 0;
    __hip_bfloat16* value_bf = (__hip_bfloat16*)(ws + o);
    o += (size_t)BN*HEADS*HW_*HDD/2;                           // 2,162,688 floats
    float* off_ws   = ws + o; o += (size_t)MTOT*128;           // 7,680,000
    float* attw_ws  = ws + o; o += (size_t)MTOT*64;            // 3,840,000
    float* asum     = ws + o; o += (size_t)NQ*DIM;             // 2,560,000
    float* slots    = ws + o; o += (size_t)NQ*DIM;             // 2,560,000
    float* hitf     = ws + o; o += (size_t)BN*NQ;              //    60,000
    float* scalev   = ws + o; o += NQ;                         //    10,000
    float* biasf    = ws + o; o += NQ;                         //    10,000
    float* ebias    = ws + o; o += BN*DIM;                     //     1,536
    // total ~75.5 MB

    k_ebias  <<<BN, 256, 0, stream>>>(lvl_emb, cam_emb, Wv, bv, ebias);
    k_mask   <<<(NQ+255)/256, 256, 0, stream>>>(bev, hitf, scalev, biasf);
    k_value  <<<dim3(HW_/64, DIM/64, BN), 256, 0, stream>>>(features, Wv, ebias, value_bf);
    k_offattn<<<(MTOT+63)/64, 256, 0, stream>>>(queries, pos_emb, Wo, bo, Wa, ba, off_ws, attw_ws);
    k_sample <<<NQ/8, 256, 0, stream>>>(value_bf, off_ws, attw_ws, ref3d, hitf, scalev, asum);
    k_gemm_nb<<<dim3((NQ+63)/64, DIM/64), 256, 0, stream>>>(asum, Wi, bi, biasf, slots, NQ);
    k_gemm_nb<<<dim3((NQ+63)/64, DIM/64), 256, 0, stream>>>(slots, Wz, bz, nullptr, out, NQ);
}

// Round 4
// 342.800 us; speedup vs baseline: 2.0950x; 1.3017x over previous
//
#include <hip/hip_runtime.h>
#include <hip/hip_bf16.h>

#define BN     6
#define NQ     10000
#define DIM    256
#define HEADS  8
#define HDD    32
#define HF_    32
#define WF_    88
#define HW_    (HF_*WF_)     /* 2816 */
#define MTOT   (BN*NQ)       /* 60000 */

typedef __attribute__((ext_vector_type(8))) unsigned short ushort8_t;
typedef __attribute__((ext_vector_type(8))) short bf16x8;
typedef __attribute__((ext_vector_type(4))) float f32x4;

static __device__ inline unsigned short f2bf(float x) {
    __hip_bfloat16 b = __float2bfloat16(x);
    return *(unsigned short*)&b;
}

// ---------------------------------------------------------------------------
// K_wcvt: f32 weights -> bf16 copies. Wv(65536), Wo(32768)+Wa(16384)->Woa,
// Wi(65536), Wz(65536).
// ---------------------------------------------------------------------------
__global__ __launch_bounds__(256)
void k_wcvt(const float* __restrict__ Wv, const float* __restrict__ Wo,
            const float* __restrict__ Wa, const float* __restrict__ Wi,
            const float* __restrict__ Wz,
            unsigned short* __restrict__ Wv_bf, unsigned short* __restrict__ Woa_bf,
            unsigned short* __restrict__ Wi_bf, unsigned short* __restrict__ Wz_bf)
{
    const int i4 = (blockIdx.x*256 + threadIdx.x) * 4;
    if (i4 < 65536) {
        float4 v;
        ushort4 p;
        v = *(const float4*)(Wv+i4); p.x=f2bf(v.x);p.y=f2bf(v.y);p.z=f2bf(v.z);p.w=f2bf(v.w);
        *(ushort4*)(Wv_bf+i4) = p;
        v = *(const float4*)(Wi+i4); p.x=f2bf(v.x);p.y=f2bf(v.y);p.z=f2bf(v.z);p.w=f2bf(v.w);
        *(ushort4*)(Wi_bf+i4) = p;
        v = *(const float4*)(Wz+i4); p.x=f2bf(v.x);p.y=f2bf(v.y);p.z=f2bf(v.z);p.w=f2bf(v.w);
        *(ushort4*)(Wz_bf+i4) = p;
    }
    if (i4 < 32768) {
        float4 v = *(const float4*)(Wo+i4);
        ushort4 p; p.x=f2bf(v.x);p.y=f2bf(v.y);p.z=f2bf(v.z);p.w=f2bf(v.w);
        *(ushort4*)(Woa_bf+i4) = p;
    }
    if (i4 < 16384) {
        float4 v = *(const float4*)(Wa+i4);
        ushort4 p; p.x=f2bf(v.x);p.y=f2bf(v.y);p.z=f2bf(v.z);p.w=f2bf(v.w);
        *(ushort4*)(Woa_bf+32768+i4) = p;
    }
}

// ---------------------------------------------------------------------------
// K0: ebias[n][j] = sum_d (lvl[d]+cam[n][d]) * W_value[j][d] + b_value[j]
// ---------------------------------------------------------------------------
__global__ __launch_bounds__(256)
void k_ebias(const float* __restrict__ lvl, const float* __restrict__ cam,
             const float* __restrict__ Wv, const float* __restrict__ bv,
             float* __restrict__ ebias)
{
    const int n = blockIdx.x;
    const int j = threadIdx.x;
    __shared__ float e[DIM];
    e[j] = lvl[j] + cam[n*DIM + j];
    __syncthreads();
    const float* w = Wv + (size_t)j*DIM;
    float s = bv[j];
    for (int d = 0; d < DIM; ++d) s += e[d]*w[d];
    ebias[n*DIM + j] = s;
}

// ---------------------------------------------------------------------------
// K_mask: per-q hit flags, count scale, bias gate.
// ---------------------------------------------------------------------------
__global__ __launch_bounds__(256)
void k_mask(const int* __restrict__ bev, float* __restrict__ hitf,
            float* __restrict__ scale, float* __restrict__ biasf)
{
    const int q = blockIdx.x*256 + threadIdx.x;
    if (q >= NQ) return;
    float cnt = 0.f;
    #pragma unroll
    for (int n = 0; n < BN; ++n) {
        int hit = 0;
        #pragma unroll
        for (int z = 0; z < 4; ++z)
            hit |= (bev[(((size_t)n*NQ + q)*4 + z)*2] != 0);
        hitf[(size_t)n*NQ + q] = (float)hit;
        cnt += (float)hit;
    }
    biasf[q] = (cnt > 0.f) ? 1.f : 0.f;
    scale[q] = 1.f / fmaxf(cnt, 1.f);
}

// ---------------------------------------------------------------------------
// K_feat: transpose feat[cam][256 d][2816 p] f32 -> featT[cam][p][d] bf16.
// 64x64 tiles through LDS.
// ---------------------------------------------------------------------------
__global__ __launch_bounds__(256)
void k_feat(const float* __restrict__ feat, unsigned short* __restrict__ featT)
{
    __shared__ float Tf[64][68];
    const int cam = blockIdx.z;
    const int d0 = blockIdx.y * 64;
    const int p0 = blockIdx.x * 64;
    const int tid = threadIdx.x;
    #pragma unroll
    for (int i = 0; i < 4; ++i) {
        const int d = (tid>>4) + i*16;
        const int p4 = (tid&15)*4;
        *(float4*)&Tf[d][p4] = *(const float4*)(feat + ((size_t)cam*DIM + d0 + d)*HW_ + p0 + p4);
    }
    __syncthreads();
    const int p = tid>>2, dq = tid&3;
    unsigned short* ob = featT + ((size_t)cam*HW_ + p0 + p)*DIM + d0;
    #pragma unroll
    for (int i = 0; i < 4; ++i) {
        const int d4 = dq*4 + i*16;
        ushort4 pk;
        pk.x = f2bf(Tf[d4+0][p]); pk.y = f2bf(Tf[d4+1][p]);
        pk.z = f2bf(Tf[d4+2][p]); pk.w = f2bf(Tf[d4+3][p]);
        *(ushort4*)(ob + d4) = pk;
    }
}

// ---------------------------------------------------------------------------
// K1: value GEMM via MFMA.  D[p][c] = featT[p][k] · Wv_bf[c][k] + ebias[c].
// Block tile 128p x 64c, K-chunks of 64.  value_bf[(cam*8+h)*HW+p][c&31].
// ---------------------------------------------------------------------------
__global__ __launch_bounds__(256)
void k_value_mfma(const unsigned short* __restrict__ featT,
                  const unsigned short* __restrict__ Wv_bf,
                  const float* __restrict__ ebias,
                  unsigned short* __restrict__ value_bf)
{
    __shared__ unsigned short Ap[128][72];
    __shared__ unsigned short Bc[64][72];
    const int cam = blockIdx.z;
    const int p0 = blockIdx.x * 128;
    const int c0 = blockIdx.y * 64;
    const int tid = threadIdx.x;
    const int lane = tid & 63, wave = tid >> 6;
    const int quad = lane >> 4, l15 = lane & 15;
    f32x4 acc[2][4] = {};
    const unsigned short* fbase = featT + ((size_t)cam*HW_ + p0)*DIM;

    for (int k0 = 0; k0 < DIM; k0 += 64) {
        #pragma unroll
        for (int i = 0; i < 4; ++i) {
            const int row = (tid>>3) + i*32;
            const int k8 = (tid&7)*8;
            *(ushort8_t*)&Ap[row][k8] = *(const ushort8_t*)(fbase + (size_t)row*DIM + k0 + k8);
        }
        #pragma unroll
        for (int i = 0; i < 2; ++i) {
            const int row = (tid>>3) + i*32;
            const int k8 = (tid&7)*8;
            *(ushort8_t*)&Bc[row][k8] = *(const ushort8_t*)(Wv_bf + (size_t)(c0+row)*DIM + k0 + k8);
        }
        __syncthreads();
        #pragma unroll
        for (int s = 0; s < 2; ++s) {
            const int kf = s*32 + quad*8;
            bf16x8 a[2], b[4];
            #pragma unroll
            for (int mt = 0; mt < 2; ++mt)
                a[mt] = *(const bf16x8*)&Ap[(wave*2+mt)*16 + l15][kf];
            #pragma unroll
            for (int nt = 0; nt < 4; ++nt)
                b[nt] = *(const bf16x8*)&Bc[nt*16 + l15][kf];
            #pragma unroll
            for (int mt = 0; mt < 2; ++mt)
                #pragma unroll
                for (int nt = 0; nt < 4; ++nt)
                    acc[mt][nt] = __builtin_amdgcn_mfma_f32_16x16x32_bf16(a[mt], b[nt], acc[mt][nt], 0,0,0);
        }
        __syncthreads();
    }
    #pragma unroll
    for (int nt = 0; nt < 4; ++nt) {
        const int c = c0 + nt*16 + l15;
        const float eb = ebias[cam*DIM + c];
        const int h = c >> 5, cc = c & 31;
        unsigned short* vb = value_bf + (size_t)(cam*HEADS + h)*HW_*HDD + cc;
        #pragma unroll
        for (int mt = 0; mt < 2; ++mt)
            #pragma unroll
            for (int r = 0; r < 4; ++r) {
                const int p = p0 + (wave*2+mt)*16 + quad*4 + r;
                vb[(size_t)p*HDD] = f2bf(acc[mt][nt][r] + eb);
            }
    }
}

// ---------------------------------------------------------------------------
// K2a: off/attn GEMM via MFMA. 64 rows x 192 cols per block; A = bf16(Qr+Pe)
// staged inline; B = Woa_bf.  K-chunks of 64.
// ---------------------------------------------------------------------------
__global__ __launch_bounds__(256)
void k_offattn(const float* __restrict__ Qr, const float* __restrict__ Pe,
               const unsigned short* __restrict__ Woa_bf,
               const float* __restrict__ boff, const float* __restrict__ battn,
               float* __restrict__ off_ws, float* __restrict__ attw_ws)
{
    __shared__ unsigned short Aq[64][72];
    __shared__ unsigned short Bw[192][72];
    const int m0 = blockIdx.x * 64;
    const int tid = threadIdx.x;
    const int lane = tid & 63, wave = tid >> 6;
    const int quad = lane >> 4, l15 = lane & 15;
    f32x4 acc[4][3] = {};
    const int n0 = wave * 48;
    const int srow = tid >> 2;
    const int sk4  = (tid & 3) * 4;

    for (int k0 = 0; k0 < DIM; k0 += 64) {
        const int m = m0 + srow;
        #pragma unroll
        for (int i = 0; i < 4; ++i) {
            const int kk = sk4 + i*16;
            float4 x = make_float4(0.f,0.f,0.f,0.f), y = x;
            if (m < MTOT) {
                x = *(const float4*)(Qr + (size_t)m*DIM + k0 + kk);
                y = *(const float4*)(Pe + (size_t)m*DIM + k0 + kk);
            }
            ushort4 pk;
            pk.x = f2bf(x.x+y.x); pk.y = f2bf(x.y+y.y);
            pk.z = f2bf(x.z+y.z); pk.w = f2bf(x.w+y.w);
            *(ushort4*)&Aq[srow][kk] = pk;
        }
        #pragma unroll
        for (int s = 0; s < 6; ++s) {
            const int row = (tid>>3) + s*32;
            const int k8 = (tid&7)*8;
            *(ushort8_t*)&Bw[row][k8] =
                *(const ushort8_t*)(Woa_bf + (size_t)row*DIM + k0 + k8);
        }
        __syncthreads();
        #pragma unroll
        for (int s = 0; s < 2; ++s) {
            const int kf = s*32 + quad*8;
            bf16x8 a[4], b[3];
            #pragma unroll
            for (int mt = 0; mt < 4; ++mt)
                a[mt] = *(const bf16x8*)&Aq[mt*16 + l15][kf];
            #pragma unroll
            for (int nt = 0; nt < 3; ++nt)
                b[nt] = *(const bf16x8*)&Bw[n0 + nt*16 + l15][kf];
            #pragma unroll
            for (int mt = 0; mt < 4; ++mt)
                #pragma unroll
                for (int nt = 0; nt < 3; ++nt)
                    acc[mt][nt] = __builtin_amdgcn_mfma_f32_16x16x32_bf16(a[mt], b[nt], acc[mt][nt], 0,0,0);
        }
        __syncthreads();
    }
    #pragma unroll
    for (int nt = 0; nt < 3; ++nt) {
        const int col = n0 + nt*16 + l15;
        const float bias = (col < 128) ? boff[col] : battn[col-128];
        #pragma unroll
        for (int mt = 0; mt < 4; ++mt) {
            #pragma unroll
            for (int r = 0; r < 4; ++r) {
                const int m = m0 + mt*16 + quad*4 + r;
                if (m >= MTOT) continue;
                const float v = acc[mt][nt][r] + bias;
                if (col < 128) off_ws [(size_t)m*128 + col]       = v;
                else           attw_ws[(size_t)m*64 + (col-128)]  = v;
            }
        }
    }
}

// ---------------------------------------------------------------------------
// K2b: sampling fused with camera reduce; writes asum in bf16.
// ---------------------------------------------------------------------------
__global__ __launch_bounds__(256)
void k_sample(const unsigned short* __restrict__ value_bf,
              const float* __restrict__ off_ws, const float* __restrict__ attw_ws,
              const float* __restrict__ ref3d, const float* __restrict__ hitf,
              const float* __restrict__ scale, unsigned short* __restrict__ asum_bf)
{
    const int q0 = blockIdx.x * 8;
    const int tid = threadIdx.x;

    __shared__ float s_off[8][128];
    __shared__ float s_att[8][64];
    __shared__ float s_ref[8][8];
    __shared__ float s_hit[BN][8];
    __shared__ float s_scl[8];

    if (tid < 48) s_hit[tid>>3][tid&7] = hitf[(size_t)(tid>>3)*NQ + q0 + (tid&7)];
    if (tid < 8)  s_scl[tid] = scale[q0 + tid];

    const int quarter = tid & 3;
    const int h  = (tid >> 2) & 7;
    const int ql = tid >> 5;

    float acc[8];
    #pragma unroll
    for (int c = 0; c < 8; ++c) acc[c] = 0.f;

    for (int n = 0; n < BN; ++n) {
        __syncthreads();
        {
            const float4* so = (const float4*)(off_ws + ((size_t)n*NQ + q0)*128);
            ((float4*)&s_off[0][0])[tid] = so[tid];
            const float2* sa = (const float2*)(attw_ws + ((size_t)n*NQ + q0)*64);
            ((float2*)&s_att[0][0])[tid] = sa[tid];
            if (tid < 64)
                (&s_ref[0][0])[tid] = (ref3d + ((size_t)n*NQ + q0)*8)[tid];
        }
        __syncthreads();

        if (s_hit[n][ql] != 0.f) {
            float lg[8];
            float mx = -1e30f;
            #pragma unroll
            for (int p = 0; p < 8; ++p) { lg[p] = s_att[ql][h*8+p]; mx = fmaxf(mx, lg[p]); }
            float ssum = 0.f;
            #pragma unroll
            for (int p = 0; p < 8; ++p) { lg[p] = __expf(lg[p]-mx); ssum += lg[p]; }
            const float inv = 1.f/ssum;

            const unsigned short* vbase =
                value_bf + (size_t)(n*HEADS + h)*HW_*HDD + quarter*8;

            #pragma unroll
            for (int p = 0; p < 8; ++p) {
                const int z = p & 3;
                const float ax = s_ref[ql][z*2+0]*WF_ + s_off[ql][h*16+p*2+0] - 0.5f;
                const float ay = s_ref[ql][z*2+1]*HF_ + s_off[ql][h*16+p*2+1] - 0.5f;
                const float fx = floorf(ax), fy = floorf(ay);
                const float dx = ax-fx, dy = ay-fy;
                const int x0 = (int)fx, y0 = (int)fy;
                const float wp = lg[p]*inv;
                #pragma unroll
                for (int oy = 0; oy < 2; ++oy) {
                    const int yi = y0 + oy;
                    const float wy = oy ? dy : 1.f-dy;
                    #pragma unroll
                    for (int ox = 0; ox < 2; ++ox) {
                        const int xi = x0 + ox;
                        const float wx = ox ? dx : 1.f-dx;
                        const bool valid = ((unsigned)xi < WF_) & ((unsigned)yi < HF_);
                        const float cw = valid ? wp*wy*wx : 0.f;
                        const int xc = min(max(xi, 0), WF_-1);
                        const int yc = min(max(yi, 0), HF_-1);
                        const ushort8_t v = *(const ushort8_t*)(vbase + (size_t)(yc*WF_ + xc)*HDD);
                        #pragma unroll
                        for (int c = 0; c < 8; ++c)
                            acc[c] += cw * __uint_as_float(((unsigned)v[c]) << 16);
                    }
                }
            }
        }
    }

    const float sc = s_scl[ql];
    ushort8_t o;
    #pragma unroll
    for (int c = 0; c < 8; ++c) o[c] = f2bf(acc[c]*sc);
    *(ushort8_t*)(asum_bf + ((size_t)(q0+ql))*DIM + h*HDD + quarter*8) = o;
}

// ---------------------------------------------------------------------------
// K3/K4: MFMA GEMM 128m x 64n: out = A_bf[m][k]·W_bf[n][k] + f(m)*bias[n].
// Writes f32 (out_f) and/or bf16 (out_b).
// ---------------------------------------------------------------------------
__global__ __launch_bounds__(256)
void k_gemm_mfma(const unsigned short* __restrict__ A_bf,
                 const unsigned short* __restrict__ W_bf,
                 const float* __restrict__ bias, const float* __restrict__ rowscale,
                 float* __restrict__ out_f, unsigned short* __restrict__ out_b, int M)
{
    __shared__ unsigned short As[128][72];
    __shared__ unsigned short Bs[64][72];
    const int m0 = blockIdx.x * 128;
    const int j0 = blockIdx.y * 64;
    const int tid = threadIdx.x;
    const int lane = tid & 63, wave = tid >> 6;
    const int quad = lane >> 4, l15 = lane & 15;
    f32x4 acc[2][4] = {};

    for (int k0 = 0; k0 < DIM; k0 += 64) {
        #pragma unroll
        for (int i = 0; i < 4; ++i) {
            const int row = (tid>>3) + i*32;
            const int k8 = (tid&7)*8;
            ushort8_t v = {0,0,0,0,0,0,0,0};
            if (m0 + row < M)
                v = *(const ushort8_t*)(A_bf + (size_t)(m0+row)*DIM + k0 + k8);
            *(ushort8_t*)&As[row][k8] = v;
        }
        #pragma unroll
        for (int i = 0; i < 2; ++i) {
            const int row = (tid>>3) + i*32;
            const int k8 = (tid&7)*8;
            *(ushort8_t*)&Bs[row][k8] = *(const ushort8_t*)(W_bf + (size_t)(j0+row)*DIM + k0 + k8);
        }
        __syncthreads();
        #pragma unroll
        for (int s = 0; s < 2; ++s) {
            const int kf = s*32 + quad*8;
            bf16x8 a[2], b[4];
            #pragma unroll
            for (int mt = 0; mt < 2; ++mt)
                a[mt] = *(const bf16x8*)&As[(wave*2+mt)*16 + l15][kf];
            #pragma unroll
            for (int nt = 0; nt < 4; ++nt)
                b[nt] = *(const bf16x8*)&Bs[nt*16 + l15][kf];
            #pragma unroll
            for (int mt = 0; mt < 2; ++mt)
                #pragma unroll
                for (int nt = 0; nt < 4; ++nt)
                    acc[mt][nt] = __builtin_amdgcn_mfma_f32_16x16x32_bf16(a[mt], b[nt], acc[mt][nt], 0,0,0);
        }
        __syncthreads();
    }
    #pragma unroll
    for (int nt = 0; nt < 4; ++nt) {
        const int j = j0 + nt*16 + l15;
        const float bj = bias[j];
        #pragma unroll
        for (int mt = 0; mt < 2; ++mt) {
            #pragma unroll
            for (int r = 0; r < 4; ++r) {
                const int m = m0 + (wave*2+mt)*16 + quad*4 + r;
                if (m >= M) continue;
                const float f = rowscale ? rowscale[m] : 1.f;
                const float v = acc[mt][nt][r] + f*bj;
                if (out_f) out_f[(size_t)m*DIM + j] = v;
                if (out_b) out_b[(size_t)m*DIM + j] = f2bf(v);
            }
        }
    }
}

// ---------------------------------------------------------------------------
extern "C" void kernel_launch(void* const* d_in, const int* in_sizes, int n_in,
                              void* d_out, int out_size, void* d_ws, size_t ws_size,
                              hipStream_t stream)
{
    const float* queries = (const float*)d_in[0];
    const float* pos_emb = (const float*)d_in[1];
    const float* lvl_emb = (const float*)d_in[2];
    const float* cam_emb = (const float*)d_in[3];
    const float* features= (const float*)d_in[4];
    const float* ref3d   = (const float*)d_in[5];
    const int*   bev     = (const int*)d_in[6];
    const float* Wv = (const float*)d_in[7];
    const float* bv = (const float*)d_in[8];
    const float* Wo = (const float*)d_in[9];
    const float* bo = (const float*)d_in[10];
    const float* Wa = (const float*)d_in[11];
    const float* ba = (const float*)d_in[12];
    const float* Wi = (const float*)d_in[13];
    const float* bi = (const float*)d_in[14];
    const float* Wz = (const float*)d_in[15];
    const float* bz = (const float*)d_in[16];
    float* out = (float*)d_out;

    char* ws = (char*)d_ws;
    size_t o = 0;
    auto alloc = [&](size_t bytes) { char* p = ws + o; o += (bytes + 255) & ~size_t(255); return p; };
    unsigned short* value_bf = (unsigned short*)alloc((size_t)BN*HEADS*HW_*HDD*2);  // 8.65 MB
    unsigned short* featT    = (unsigned short*)alloc((size_t)BN*HW_*DIM*2);        // 8.65 MB
    float* off_ws   = (float*)alloc((size_t)MTOT*128*4);                            // 30.7 MB
    float* attw_ws  = (float*)alloc((size_t)MTOT*64*4);                             // 15.4 MB
    unsigned short* asum_bf  = (unsigned short*)alloc((size_t)NQ*DIM*2);            // 5.1 MB
    unsigned short* slots_bf = (unsigned short*)alloc((size_t)NQ*DIM*2);            // 5.1 MB
    unsigned short* Wv_bf  = (unsigned short*)alloc(65536*2);
    unsigned short* Woa_bf = (unsigned short*)alloc(49152*2);
    unsigned short* Wi_bf  = (unsigned short*)alloc(65536*2);
    unsigned short* Wz_bf  = (unsigned short*)alloc(65536*2);
    float* hitf   = (float*)alloc((size_t)BN*NQ*4);
    float* scalev = (float*)alloc(NQ*4);
    float* biasf  = (float*)alloc(NQ*4);
    float* ebias  = (float*)alloc(BN*DIM*4);
    // total ~74 MB

    k_wcvt  <<<64, 256, 0, stream>>>(Wv, Wo, Wa, Wi, Wz, Wv_bf, Woa_bf, Wi_bf, Wz_bf);
    k_ebias <<<BN, 256, 0, stream>>>(lvl_emb, cam_emb, Wv, bv, ebias);
    k_mask  <<<(NQ+255)/256, 256, 0, stream>>>(bev, hitf, scalev, biasf);
    k_feat  <<<dim3(HW_/64, DIM/64, BN), 256, 0, stream>>>(features, featT);
    k_value_mfma<<<dim3(HW_/128, DIM/64, BN), 256, 0, stream>>>(featT, Wv_bf, ebias, value_bf);
    k_offattn<<<(MTOT+63)/64, 256, 0, stream>>>(queries, pos_emb, Woa_bf, bo, ba, off_ws, attw_ws);
    k_sample <<<NQ/8, 256, 0, stream>>>(value_bf, off_ws, attw_ws, ref3d, hitf, scalev, asum_bf);
    k_gemm_mfma<<<dim3((NQ+127)/128, DIM/64), 256, 0, stream>>>(asum_bf, Wi_bf, bi, biasf, nullptr, slots_bf, NQ);
    k_gemm_mfma<<<dim3((NQ+127)/128, DIM/64), 256, 0, stream>>>(slots_bf, Wz_bf, bz, nullptr, out, nullptr, NQ);
}